// Round 4
// baseline (230.918 us; speedup 1.0000x reference)
//
#include <hip/hip_runtime.h>

#define NODES 10000
#define BATCH 8
#define CH    128
#define KNB   16
#define CO    256

typedef __bf16 bf16x8 __attribute__((ext_vector_type(8)));
typedef float  f32x4  __attribute__((ext_vector_type(4)));

__device__ __forceinline__ unsigned short f2bf(float f) {
  unsigned u = __float_as_uint(f);
  u = (u + 0x7FFFu + ((u >> 16) & 1u)) >> 16;   // RNE
  return (unsigned short)u;
}
__device__ __forceinline__ unsigned pk2(float a, float b) {
  return (unsigned)f2bf(a) | ((unsigned)f2bf(b) << 16);
}
// max of packed non-negative bf16 == packed u16 max (relu guarantees >=0)
__device__ __forceinline__ unsigned pkmax(unsigned a, unsigned b) {
  unsigned d;
  asm("v_pk_max_u16 %0, %1, %2" : "=v"(d) : "v"(a), "v"(b));
  return d;
}
__device__ __forceinline__ uint4 pkmax4(uint4 a, uint4 b) {
  a.x = pkmax(a.x, b.x); a.y = pkmax(a.y, b.y);
  a.z = pkmax(a.z, b.z); a.w = pkmax(a.w, b.w);
  return a;
}
__device__ __forceinline__ bf16x8 asbf8(uint4 u) {
  union { uint4 u; bf16x8 b; } c; c.u = u; return c.b;
}

// ---------------------------------------------------------------------------
// fp32 -> bf16 weight conversion (row-major [d][k] kept)
// ---------------------------------------------------------------------------
__global__ __launch_bounds__(256) void prep(
    const float* __restrict__ W1, const float* __restrict__ Wp,
    const float* __restrict__ W2,
    unsigned short* __restrict__ W1b, unsigned short* __restrict__ Wpb,
    unsigned short* __restrict__ W2b)
{
  int i = blockIdx.x * 256 + threadIdx.x;   // float4 index, 24576 total
  const float* src; unsigned short* dst; int off;
  if (i < 4096)      { src = W1; dst = W1b; off = i; }
  else if (i < 8192) { src = Wp; dst = Wpb; off = i - 4096; }
  else               { src = W2; dst = W2b; off = i - 8192; }
  float4 v = ((const float4*)src)[off];
  ushort4 o;
  o.x = f2bf(v.x); o.y = f2bf(v.y); o.z = f2bf(v.z); o.w = f2bf(v.w);
  ((ushort4*)dst)[off] = o;
}

// ---------------------------------------------------------------------------
// Fused h = relu(W1 x + b1), z = relu(Wp h + bp), both bf16 [b][n][128].
// WAVE-INDEPENDENT: each wave owns 16 nodes, no __syncthreads anywhere.
// x B-fragments loaded straight to registers (quad-coalesced dword loads);
// h round-trips D-layout -> B-layout through a private 4KB LDS slice.
// A (W1/Wp) streamed from global (L2-hot) with per-dt prefetch.
// ---------------------------------------------------------------------------
__global__ __launch_bounds__(256) void fused_hz(
    const unsigned short* __restrict__ W1b, const float* __restrict__ b1,
    const unsigned short* __restrict__ Wpb, const float* __restrict__ bp,
    const float* __restrict__ x,
    unsigned short* __restrict__ h_t, unsigned short* __restrict__ z_t)
{
  const int b    = blockIdx.y;
  const int t    = threadIdx.x;
  const int w    = t >> 6, lane = t & 63;
  const int lm   = lane & 15, q = lane >> 4;
  const int nw0  = blockIdx.x * 64 + w * 16;

  __shared__ __align__(16) unsigned short Hs_all[4][16 * 128];  // 4KB/wave
  char* Hs = (char*)Hs_all[w];

  const int node = nw0 + lm;
  const int gn   = (node < NODES) ? node : (NODES - 1);

  // ---- load this lane's x B-fragment elements: x[c][gn], c = kt*32+q*8+j
  const float* X = x + (size_t)b * CH * NODES + gn;
  float xv[4][8];
#pragma unroll
  for (int kt = 0; kt < 4; ++kt)
#pragma unroll
    for (int j = 0; j < 8; ++j)
      xv[kt][j] = X[(size_t)(kt * 32 + q * 8 + j) * NODES];

  uint4 B1[4];
#pragma unroll
  for (int kt = 0; kt < 4; ++kt) {
    B1[kt].x = pk2(xv[kt][0], xv[kt][1]);
    B1[kt].y = pk2(xv[kt][2], xv[kt][3]);
    B1[kt].z = pk2(xv[kt][4], xv[kt][5]);
    B1[kt].w = pk2(xv[kt][6], xv[kt][7]);
  }

  // ---- phase 1: h = relu(W1 x + b1), 8 dt tiles of 16 d, prefetched A
  uint4 a_cur[4], a_nxt[4];
#pragma unroll
  for (int kt = 0; kt < 4; ++kt)
    a_cur[kt] = *(const uint4*)(W1b + (size_t)(lm) * CH + kt * 32 + q * 8);

#pragma unroll
  for (int dt = 0; dt < 8; ++dt) {
    if (dt < 7) {
#pragma unroll
      for (int kt = 0; kt < 4; ++kt)
        a_nxt[kt] = *(const uint4*)(W1b + (size_t)((dt + 1) * 16 + lm) * CH
                                    + kt * 32 + q * 8);
    }
    f32x4 acc = (f32x4){0.f, 0.f, 0.f, 0.f};
#pragma unroll
    for (int kt = 0; kt < 4; ++kt)
      acc = __builtin_amdgcn_mfma_f32_16x16x32_bf16(
          asbf8(a_cur[kt]), asbf8(B1[kt]), acc, 0, 0, 0);

    const int d0 = dt * 16 + q * 4;
    float4 bi = *(const float4*)(b1 + d0);
    ushort4 o;
    o.x = f2bf(fmaxf(acc[0] + bi.x, 0.f));
    o.y = f2bf(fmaxf(acc[1] + bi.y, 0.f));
    o.z = f2bf(fmaxf(acc[2] + bi.z, 0.f));
    o.w = f2bf(fmaxf(acc[3] + bi.w, 0.f));
    if (node < NODES)
      *(ushort4*)(h_t + ((size_t)b * NODES + node) * CH + d0) = o;
    // LDS: row = node-in-wave (lm), chunk = d0>>3, half = q&1, swizzled
    const int chunk = dt * 2 + (q >> 1);
    *(ushort4*)(Hs + lm * 256 + ((chunk ^ (lm & 7)) << 4) + ((q & 1) << 3)) = o;
#pragma unroll
    for (int kt = 0; kt < 4; ++kt) a_cur[kt] = a_nxt[kt];
  }

  // ---- h D-layout -> B-fragments (same wave: waitcnt only, no barrier)
  uint4 B2[4];
#pragma unroll
  for (int kt = 0; kt < 4; ++kt)
    B2[kt] = *(const uint4*)(Hs + lm * 256 + (((kt * 4 + q) ^ (lm & 7)) << 4));

  // ---- phase 2: z = relu(Wp h + bp)
#pragma unroll
  for (int kt = 0; kt < 4; ++kt)
    a_cur[kt] = *(const uint4*)(Wpb + (size_t)(lm) * CH + kt * 32 + q * 8);

#pragma unroll
  for (int dt = 0; dt < 8; ++dt) {
    if (dt < 7) {
#pragma unroll
      for (int kt = 0; kt < 4; ++kt)
        a_nxt[kt] = *(const uint4*)(Wpb + (size_t)((dt + 1) * 16 + lm) * CH
                                    + kt * 32 + q * 8);
    }
    f32x4 acc = (f32x4){0.f, 0.f, 0.f, 0.f};
#pragma unroll
    for (int kt = 0; kt < 4; ++kt)
      acc = __builtin_amdgcn_mfma_f32_16x16x32_bf16(
          asbf8(a_cur[kt]), asbf8(B2[kt]), acc, 0, 0, 0);

    const int d0 = dt * 16 + q * 4;
    float4 bi = *(const float4*)(bp + d0);
    if (node < NODES) {
      ushort4 o;
      o.x = f2bf(fmaxf(acc[0] + bi.x, 0.f));
      o.y = f2bf(fmaxf(acc[1] + bi.y, 0.f));
      o.z = f2bf(fmaxf(acc[2] + bi.z, 0.f));
      o.w = f2bf(fmaxf(acc[3] + bi.w, 0.f));
      *(ushort4*)(z_t + ((size_t)b * NODES + node) * CH + d0) = o;
    }
#pragma unroll
    for (int kt = 0; kt < 4; ++kt) a_cur[kt] = a_nxt[kt];
  }
}

// ---------------------------------------------------------------------------
// out[b][d][n] = relu(W2 @ [h[n]; max_k z[idx[n,k]]] + b2), d=256, K=256.
// WAVE-INDEPENDENT: 128-thread blocks, each wave owns 32 nodes, no barriers.
// Wave stages h + gather-max (packed-u16 bf16, quad-coalesced 64B loads)
// into its private 16KB LDS slice, pulls B-fragments into 64 VGPRs once,
// then sweeps all 256 output channels streaming W2 with 4-deep A prefetch.
// b = bid&7 keeps each batch's 2.56MB z slab affine to one XCD L2.
// ---------------------------------------------------------------------------
__global__ __launch_bounds__(128) void out_kernel(
    const unsigned short* __restrict__ h_t, const unsigned short* __restrict__ z_t,
    const int* __restrict__ e0, const unsigned short* __restrict__ W2b,
    const float* __restrict__ b2, float* __restrict__ out)
{
  const int bid = blockIdx.x;
  const int b   = bid & 7;
  const int t   = threadIdx.x;
  const int w   = t >> 6, lane = t & 63;
  const int nw0 = (bid >> 3) * 64 + w * 32;

  __shared__ __align__(16) unsigned short cat_all[2][32 * 256];  // 16KB/wave
  char* cat = (char*)cat_all[w];

  // ---- stage h + gather-max: thread = (nl4 = lane>>2, c = lane&3)
  const int nl4 = lane >> 2, c = lane & 3;
  const char* Zb = (const char*)z_t + (size_t)b * NODES * (CH * 2);
#pragma unroll
  for (int p = 0; p < 2; ++p) {
    const int nl = p * 16 + nl4;
    int gn = nw0 + nl; if (gn >= NODES) gn = NODES - 1;

    // h row: quad covers 64B chunks {4j+c}
    const char* H = (const char*)h_t + ((size_t)b * NODES + gn) * (CH * 2);
    uint4 hv[4];
#pragma unroll
    for (int j = 0; j < 4; ++j)
      hv[j] = *(const uint4*)(H + ((4 * j + c) << 4));

    // neighbor indices (quad-redundant, L1-served)
    const int* ep = e0 + ((size_t)b * NODES + gn) * KNB;
    unsigned idxv[KNB];
#pragma unroll
    for (int jq = 0; jq < 4; ++jq) {
      uint4 iv = *(const uint4*)(ep + jq * 4);
      idxv[jq * 4 + 0] = iv.x; idxv[jq * 4 + 1] = iv.y;
      idxv[jq * 4 + 2] = iv.z; idxv[jq * 4 + 3] = iv.w;
    }

    uint4 m[4];
#pragma unroll
    for (int j = 0; j < 4; ++j) m[j] = make_uint4(0u, 0u, 0u, 0u);
#pragma unroll
    for (int k = 0; k < KNB; ++k) {
      const char* pz = Zb + (size_t)idxv[k] * (CH * 2);
#pragma unroll
      for (int j = 0; j < 4; ++j)
        m[j] = pkmax4(m[j], *(const uint4*)(pz + ((4 * j + c) << 4)));
    }

#pragma unroll
    for (int j = 0; j < 4; ++j) {
      const int ch = 4 * j + c;            // h chunks 0..15
      *(uint4*)(cat + nl * 512 + ((ch ^ (nl & 7)) << 4)) = hv[j];
      const int cz = 16 + 4 * j + c;       // z chunks 16..31
      *(uint4*)(cat + nl * 512 + ((cz ^ (nl & 7)) << 4)) = m[j];
    }
  }

  // ---- pull B-fragments to registers (intra-wave waitcnt only)
  const int lm = lane & 15, q = lane >> 4;
  uint4 Bf[2][8];
#pragma unroll
  for (int nt = 0; nt < 2; ++nt)
#pragma unroll
    for (int kt = 0; kt < 8; ++kt)
      Bf[nt][kt] = *(const uint4*)(cat + (nt * 16 + lm) * 512
                                   + (((kt * 4 + q) ^ (lm & 7)) << 4));

  // ---- sweep 256 output channels: s = dt*2 + half, 4 A-frags per step
  uint4 a_cur[4], a_nxt[4];
#pragma unroll
  for (int kt = 0; kt < 4; ++kt)
    a_cur[kt] = *(const uint4*)(W2b + (size_t)lm * CO + kt * 32 + q * 8);

  f32x4 acc0 = (f32x4){0.f, 0.f, 0.f, 0.f};
  f32x4 acc1 = (f32x4){0.f, 0.f, 0.f, 0.f};

#pragma unroll
  for (int s = 0; s < 32; ++s) {
    const int dt = s >> 1, half = s & 1;
    if (s < 31) {
      const int dn = (s + 1) >> 1, hn = (s + 1) & 1;
#pragma unroll
      for (int kt = 0; kt < 4; ++kt)
        a_nxt[kt] = *(const uint4*)(W2b + (size_t)(dn * 16 + lm) * CO
                                    + (hn * 4 + kt) * 32 + q * 8);
    }
#pragma unroll
    for (int kt = 0; kt < 4; ++kt) {
      const int ktg = half * 4 + kt;
      acc0 = __builtin_amdgcn_mfma_f32_16x16x32_bf16(
          asbf8(a_cur[kt]), asbf8(Bf[0][ktg]), acc0, 0, 0, 0);
      acc1 = __builtin_amdgcn_mfma_f32_16x16x32_bf16(
          asbf8(a_cur[kt]), asbf8(Bf[1][ktg]), acc1, 0, 0, 0);
    }
    if (half == 1) {
      const int d0 = dt * 16 + q * 4;
      float4 bi = *(const float4*)(b2 + d0);
      float bv[4] = {bi.x, bi.y, bi.z, bi.w};
      f32x4 aa[2] = {acc0, acc1};
#pragma unroll
      for (int nt = 0; nt < 2; ++nt) {
        const int gn = nw0 + nt * 16 + lm;
        if (gn < NODES) {
          float* op = out + (size_t)(b * CO + d0) * NODES + gn;
#pragma unroll
          for (int r = 0; r < 4; ++r)
            op[(size_t)r * NODES] = fmaxf(aa[nt][r] + bv[r], 0.f);
        }
      }
      acc0 = (f32x4){0.f, 0.f, 0.f, 0.f};
      acc1 = (f32x4){0.f, 0.f, 0.f, 0.f};
    }
#pragma unroll
    for (int kt = 0; kt < 4; ++kt) a_cur[kt] = a_nxt[kt];
  }
}

// ---------------------------------------------------------------------------
extern "C" void kernel_launch(void* const* d_in, const int* in_sizes, int n_in,
                              void* d_out, int out_size, void* d_ws, size_t ws_size,
                              hipStream_t stream) {
  const float* x  = (const float*)d_in[0];
  const int*   ei = (const int*)d_in[1];   // (2,B,N,K); first half = targets
  const float* W1 = (const float*)d_in[2];
  const float* b1 = (const float*)d_in[3];
  const float* Wp = (const float*)d_in[4];
  const float* bp = (const float*)d_in[5];
  const float* W2 = (const float*)d_in[6];
  const float* b2 = (const float*)d_in[7];
  float* out = (float*)d_out;

  unsigned short* ws  = (unsigned short*)d_ws;
  unsigned short* h_t = ws;                                   // [B][N][128] bf16
  unsigned short* z_t = h_t + (size_t)BATCH * NODES * CH;     // [B][N][128] bf16
  unsigned short* W1b = z_t + (size_t)BATCH * NODES * CH;
  unsigned short* Wpb = W1b + CH * CH;
  unsigned short* W2b = Wpb + CH * CH;

  prep<<<96, 256, 0, stream>>>(W1, Wp, W2, W1b, Wpb, W2b);

  const int NT = (NODES + 63) / 64;   // 157
  fused_hz<<<dim3(NT, BATCH), 256, 0, stream>>>(W1b, b1, Wpb, bp, x, h_t, z_t);
  out_kernel<<<BATCH * NT, 128, 0, stream>>>(h_t, z_t, ei, W2b, b2, out);
}